// Round 1
// 227.150 us; speedup vs baseline: 1.0243x; 1.0243x over previous
//
#include <hip/hip_runtime.h>

// SwitchTransformersLoadBalancer:
//   x: (B=64, C=8, H=256, W=256) f32, accumulator: (256, 8) f32
//   out = one_hot(argmax_c (x_c - log(mean(acc[:,c]))))   [proved R0/R1, absmax 0]
// Mandatory traffic: 128 MiB read + 128 MiB write -> ~41 us floor at 6.3 TB/s.
// R3: 4x thread coarsening + depth-2 software pipeline.
//   - grid 4096 -> 1024 blocks; each thread handles 4 float4-groups/channel,
//     double-buffered so next group's 8 loads are in flight during compute/store
//     of the current group (previous version had zero loads in flight during
//     its compute+store phase -> ~3.7 TB/s effective).
//   - batch index b is now block-uniform -> SGPR base addressing.
//   - nontemporal loads (x is read-once) + nontemporal stores (write-once).
//   - per-block accumulator reduce amortized 4x.

#define PLANE4 16384   // plane stride in float4 units (65536 floats)

typedef float fvec4 __attribute__((ext_vector_type(4)));

__device__ __forceinline__ void load_group(fvec4 (&u)[8], const fvec4* __restrict__ xb,
                                           int p4) {
    #pragma unroll
    for (int c = 0; c < 8; ++c)
        u[c] = __builtin_nontemporal_load(xb + p4 + c * PLANE4);
}

__device__ __forceinline__ void proc_group(const fvec4 (&u)[8], const double (&ln)[8],
                                           fvec4* __restrict__ ob, int p4) {
    // f64 argmax (exact vs f32 reference; strict > = first-index ties)
    double best0 = (double)u[0].x - ln[0];
    double best1 = (double)u[0].y - ln[0];
    double best2 = (double)u[0].z - ln[0];
    double best3 = (double)u[0].w - ln[0];
    int idx0 = 0, idx1 = 0, idx2 = 0, idx3 = 0;

    #pragma unroll
    for (int c = 1; c < 8; ++c) {
        double d;
        d = (double)u[c].x - ln[c]; if (d > best0) { best0 = d; idx0 = c; }
        d = (double)u[c].y - ln[c]; if (d > best1) { best1 = d; idx1 = c; }
        d = (double)u[c].z - ln[c]; if (d > best2) { best2 = d; idx2 = c; }
        d = (double)u[c].w - ln[c]; if (d > best3) { best3 = d; idx3 = c; }
    }

    #pragma unroll
    for (int c = 0; c < 8; ++c) {
        fvec4 o;
        o.x = (idx0 == c) ? 1.0f : 0.0f;
        o.y = (idx1 == c) ? 1.0f : 0.0f;
        o.z = (idx2 == c) ? 1.0f : 0.0f;
        o.w = (idx3 == c) ? 1.0f : 0.0f;
        __builtin_nontemporal_store(o, ob + p4 + c * PLANE4);
    }
}

__global__ __launch_bounds__(256) void fused_route_kernel(
        const float* __restrict__ x,
        const float* __restrict__ acc,
        float* __restrict__ out) {
    int t     = threadIdx.x;
    int base4 = blockIdx.x << 10;     // block's first float4 within B*H*W/4
    int b     = base4 >> 14;          // 16384 float4 per plane -> block-uniform batch
    int p4    = (base4 & 16383) + t;  // group-0 float4 offset inside plane

    const fvec4* xb = (const fvec4*)(x + ((size_t)(b * 8) << 16));
    fvec4*       ob = (fvec4*)(out + ((size_t)(b * 8) << 16));

    // ---- issue group-0 streaming loads first (independent of the reduce) ----
    fvec4 ua[8], ub[8];
    load_group(ua, xb, p4);

    // ---- per-block lognorm: 8 KB accumulator -> LDS reduce -> log(mean) ----
    __shared__ double part[256];
    __shared__ double lns[8];
    {
        int c = t & 7;        // channel
        int g = t >> 3;       // row group, 0..31
        double s = 0.0;
        #pragma unroll
        for (int k = 0; k < 8; ++k) s += (double)acc[(g * 8 + k) * 8 + c];
        part[t] = s;
    }
    __syncthreads();
    if (t < 8) {
        double tot = 0.0;
        #pragma unroll
        for (int g2 = 0; g2 < 32; ++g2) tot += part[g2 * 8 + t];
        lns[t] = log(tot * (1.0 / 256.0));
    }
    __syncthreads();

    double ln[8];
    #pragma unroll
    for (int c = 0; c < 8; ++c) ln[c] = lns[c];   // same-address -> LDS broadcast

    // ---- depth-2 pipelined groups: load(g+1) in flight during proc(g) ----
    load_group(ub, xb, p4 + 256);     // group 1
    proc_group(ua, ln, ob, p4);       // group 0
    load_group(ua, xb, p4 + 512);     // group 2
    proc_group(ub, ln, ob, p4 + 256); // group 1
    load_group(ub, xb, p4 + 768);     // group 3
    proc_group(ua, ln, ob, p4 + 512); // group 2
    proc_group(ub, ln, ob, p4 + 768); // group 3
}

extern "C" void kernel_launch(void* const* d_in, const int* in_sizes, int n_in,
                              void* d_out, int out_size, void* d_ws, size_t ws_size,
                              hipStream_t stream) {
    const float* x   = (const float*)d_in[0];   // (64, 8, 256, 256)
    const float* acc = (const float*)d_in[1];   // (256, 8)
    float*       out = (float*)d_out;           // (64, 8, 256, 256)
    (void)d_ws; (void)ws_size;

    // B*H*W/4 = 1,048,576 float4; 4 float4/thread -> 1024 blocks x 256 threads.
    fused_route_kernel<<<1024, 256, 0, stream>>>(x, acc, out);
}